// Round 16
// baseline (71.249 us; speedup 1.0000x reference)
//
#include <hip/hip_runtime.h>

// Chamfer distance, B=16, N=M=4096, D=3, fp32.
// v17 DISCRIMINATOR: R15 hit the additive-model floor exactly (v_min 13.7us
// + MFMA 6.9us = 20.6 = observed chamfer). Only path lower: break MFMA/VALU
// additivity (-> max() = 13.7). Cause (i) SIMD issue-port serialization =>
// unfixable; cause (ii) only 4 waves/SIMD co-resident to hide each wave's
// MFMA->v_min stall. This round tests (ii) at IDENTICAL numerics: split
// targets 2048/block (32KB LDS) -> 1024 blocks = 4 blocks/CU = 8 waves/SIMD;
// halves merged via monotone-uint atomicMin (exact, order-independent =>
// absmax bit-identical 0.1167). Same MFMA/v_min totals per SIMD.
// Pre-committed: neutral/regress => additivity is structural, R15 is the
// formulation floor, ROOFLINE next round.
// Numerics = R15 verbatim (passed, 0.1167 vs 0.1206): legacy
// v_mfma_f32_32x32x8bf16_1k, K=8: A={Xh,Yh,Zh,xl|yl,zl,nt,ntl},
// B={mx,my,mz,mx|my,mz,1,1}, m=RNE(-2q), every word pack2-built both sides
// (halfword order cancels). C/D: col=lane&31, min over 16 regs +
// shfl_xor(32). NO inline asm (R7-9 corrupts, R11 deoptimizes).

#define CB 16
#define CN 4096
#define CM 4096
#define WVS 8
#define QPW 32               // queries per wave (one 32-col tile)
#define QPB (WVS * QPW)      // 256 queries per block
#define TPH 2048             // targets per block (half the cloud)
#define NTT (TPH / 32)       // 64 target tiles

typedef float f32x16 __attribute__((ext_vector_type(16)));
typedef short bf16x4 __attribute__((ext_vector_type(4)));
typedef unsigned int u32;
typedef u32 u32x2 __attribute__((ext_vector_type(2)));

__device__ __forceinline__ u32 pack2(float a, float b) {
    return __builtin_amdgcn_perm(__float_as_uint(b), __float_as_uint(a),
                                 0x07060302u);
}
__device__ __forceinline__ float hi_f(float a) {     // bf16_trunc as f32
    return __uint_as_float(__float_as_uint(a) & 0xFFFF0000u);
}
__device__ __forceinline__ float rne_bf(float f) {   // RNE-to-bf16 as f32
    u32 u = __float_as_uint(f);
    u32 r = (u + 0x7FFFu + ((u >> 16) & 1u)) & 0xFFFF0000u;
    return __uint_as_float(r);
}

__global__ void init_out(unsigned* __restrict__ out)
{
    out[blockIdx.x * 512 + threadIdx.x] = 0x7F800000u;  // +inf bits
}

// grid: (16 qtiles x 2 thalves, 16 batches, 2 dirs) = 1024 blocks x 512 thr.
__global__ __launch_bounds__(512, 8) void chamfer_mfma(
    const float* __restrict__ x1, const float* __restrict__ x2,
    unsigned* __restrict__ out)
{
    const int dir   = blockIdx.z;
    const int b     = blockIdx.y;
    const int qtile = blockIdx.x & 15;   // 256-query tile
    const int thalf = blockIdx.x >> 4;   // 2048-target half

    const float* __restrict__ qraw = (dir ? x2 : x1) + (size_t)b * CN * 3;
    const float* __restrict__ traw = (dir ? x1 : x2) + (size_t)b * CM * 3
                                   + (size_t)thalf * TPH * 3;
    unsigned* __restrict__ o = out + (dir ? ((size_t)CB * CN + (size_t)b * CM)
                                          : ((size_t)b * CN)) + qtile * QPB;

    // [tile][64]: entries 0-31 = rows' k0-3 words, 32-63 = k4-7. 32 KB.
    __shared__ u32x2 AI[NTT * 64];

    const int tid  = threadIdx.x;
    const int lane = tid & 63;
    const int wave = __builtin_amdgcn_readfirstlane(tid >> 6);
    const int col  = lane & 31;
    const int h    = lane >> 5;

    // ---- Stage 2048 targets: thread packs targets {tid + 512j, j=0..3}.
    #pragma unroll
    for (int j = 0; j < 4; ++j) {
        const int r = 512 * j + tid;
        const float* p = traw + 3 * r;
        float X = p[0], Y = p[1], Zc = p[2];
        float xl = X  - hi_f(X);
        float yl = Y  - hi_f(Y);
        float zl = Zc - hi_f(Zc);
        float nt  = fmaf(X, X, fmaf(Y, Y, Zc * Zc));
        float ntl = nt - hi_f(nt);
        const int e = (r >> 5) * 64 + (r & 31);
        AI[e]      = (u32x2){pack2(X, Y),   pack2(Zc, xl)};   // k0..k3
        AI[e + 32] = (u32x2){pack2(yl, zl), pack2(nt, ntl)};  // k4..k7
    }

    // ---- Query: wave covers [qtile*256 + wave*32, +32); lane's col.
    float nq;
    bf16x4 bq;
    {
        const float* qp = qraw + (size_t)3 * (qtile * QPB + wave * QPW + col);
        float qx = qp[0], qy = qp[1], qz = qp[2];
        nq = fmaf(qx, qx, fmaf(qy, qy, qz * qz));
        float mx = rne_bf(-2.f * qx);
        float my = rne_bf(-2.f * qy);
        float mz = rne_bf(-2.f * qz);
        u32x2 w;
        if (h == 0)
            w = (u32x2){pack2(mx, my), pack2(mz, mx)};        // k0..k3
        else
            w = (u32x2){pack2(my, mz), pack2(1.0f, 1.0f)};    // k4..k7
        bq = __builtin_bit_cast(bf16x4, w);
    }

    float best = 1e30f;
    __syncthreads();

    // ---- Sweep 64 tiles: 1 ds_read_b64 + 1 MFMA + 16-fminf tree. Unroll 4.
    #pragma unroll 1
    for (int t = 0; t < NTT; t += 4) {
        #pragma unroll
        for (int u = 0; u < 4; ++u) {
            bf16x4 af = __builtin_bit_cast(bf16x4, AI[(t + u) * 64 + lane]);
            f32x16 acc = __builtin_amdgcn_mfma_f32_32x32x8bf16_1k(
                af, bq, (f32x16)(0.f), 0, 0, 0);
            float t0 = fminf(fminf(acc[0],  acc[1]),  acc[2]);
            float t1 = fminf(fminf(acc[3],  acc[4]),  acc[5]);
            float t2 = fminf(fminf(acc[6],  acc[7]),  acc[8]);
            float t3 = fminf(fminf(acc[9],  acc[10]), acc[11]);
            float t4 = fminf(fminf(acc[12], acc[13]), acc[14]);
            float u0 = fminf(fminf(t0, t1), t2);
            float u1 = fminf(fminf(t3, t4), acc[15]);
            best = fminf(fminf(best, u0), u1);
        }
    }

    // ---- Combine half-row groups, add |q|^2, clamp, atomic-merge halves.
    float v = fminf(best, __shfl_xor(best, 32));
    if (lane < 32) {
        float val = fmaxf(v + nq, 0.f);
        atomicMin(o + wave * QPW + col, __float_as_uint(val));
    }
}

extern "C" void kernel_launch(void* const* d_in, const int* in_sizes, int n_in,
                              void* d_out, int out_size, void* d_ws, size_t ws_size,
                              hipStream_t stream) {
    const float* x1 = (const float*)d_in[0];   // [B,N,3]
    const float* x2 = (const float*)d_in[1];   // [B,M,3]
    unsigned* out = (unsigned*)d_out;

    init_out<<<dim3(2 * CB * CN / 512), 512, 0, stream>>>(out);
    chamfer_mfma<<<dim3(32, CB, 2), 512, 0, stream>>>(x1, x2, out);
}

// Round 17
// 68.296 us; speedup vs baseline: 1.0432x; 1.0432x over previous
//
#include <hip/hip_runtime.h>

// Chamfer distance, B=16, N=M=4096, D=3, fp32. FINAL (R15 restored).
//
// Session floor argument (R16 discriminator closed it):
//  - v_min floor: 536.9M distances x 1 v_min each = 8192 wave-inst/SIMD
//    x 4 cyc sustained f32 issue = 13.7us (min not MFMA-expressible).
//  - MFMA floor at cheapest-per-pair shape (32x32x8 legacy, 1024 pairs per
//    8.07 cyc/CU, m119): 512 MFMA/SIMD x 32.3 cyc = 6.9us.
//  - R16 proved the two ADD at the SIMD issue port (8 waves/SIMD at
//    identical numerics: no gain): floor = 20.6us. R15 measures chamfer
//    = 68.6 - ~48 harness fill/overhead = 20.6us. ON the floor.
//
// Session-verified constraints baked in:
//  - NO inline asm in MFMA kernels (R7-9: asm reading MFMA dests corrupts,
//    bit-identical absmax 17.2 across 3 variants; R11: asm on VALU values
//    deoptimizes +40% via copies/broken interleave). Pure fminf only.
//  - gfx950-new 32x32x16 bf16 MFMA has asymmetric A/B k-maps (R5 failed);
//    legacy v_mfma_f32_32x32x8bf16_1k is symmetric and verified (R15).
//  - pack2 (v_perm) halfword order is convention-dependent: use it for
//    EVERY word on BOTH A and B sides, positionally matched, so the order
//    cancels in the dot product (R8/R11-verified).
//  - fp32 issue is ~4 cyc/wave-inst sustained regardless of VOP2/VOP3 mix
//    (R1-R3 tri-fit); v_pk_* fp32 runs at 8 cyc => no packed-min gain.
//
// Numerics: d = |t|^2 - 2 t.q + |q|^2, K=8 dot: A={Xh,Yh,Zh,xl|yl,zl,nt,
// ntl} (trunc splits, nt=|t|^2 f32), B={mx,my,mz,mx|my,mz,1,1}, m=RNE(-2q).
// absmax 0.1167 vs threshold 0.1206 (deterministic inputs -> stable).
// C/D map (m74/m101): col=lane&31 -> min over 16 regs + shfl_xor(32).
// Whole 4096-target cloud staged once in 64KB LDS; 256 queries/block in
// registers; direct stores, no atomics, single launch.
// grid: (16 qtiles, 16 batches, 2 dirs) = 512 blocks x 512 thr (2/CU).

#define CB 16
#define CN 4096
#define CM 4096
#define WVS 8
#define QPW 32               // queries per wave (one 32-col tile)
#define QPB (WVS * QPW)      // 256 queries per block
#define NTT (CM / 32)        // 128 target tiles (whole cloud in LDS)

typedef float f32x16 __attribute__((ext_vector_type(16)));
typedef short bf16x4 __attribute__((ext_vector_type(4)));
typedef unsigned int u32;
typedef u32 u32x2 __attribute__((ext_vector_type(2)));

// pack2(a,b): halfwords = bf16_trunc(a), bf16_trunc(b); order is
// convention-dependent but positionally matched on A and B sides, so it
// cancels in the dot product. (R11-R15-verified.)
__device__ __forceinline__ u32 pack2(float a, float b) {
    return __builtin_amdgcn_perm(__float_as_uint(b), __float_as_uint(a),
                                 0x07060302u);
}
__device__ __forceinline__ float hi_f(float a) {     // bf16_trunc as f32
    return __uint_as_float(__float_as_uint(a) & 0xFFFF0000u);
}
__device__ __forceinline__ float rne_bf(float f) {   // RNE-to-bf16 as f32
    u32 u = __float_as_uint(f);
    u32 r = (u + 0x7FFFu + ((u >> 16) & 1u)) & 0xFFFF0000u;
    return __uint_as_float(r);
}

// grid: (16 qtiles, 16 batches, 2 dirs) = 512 blocks x 512 thr, 1 launch.
__global__ __launch_bounds__(512, 4) void chamfer_mfma(
    const float* __restrict__ x1, const float* __restrict__ x2,
    float* __restrict__ out)
{
    const int dir   = blockIdx.z;
    const int b     = blockIdx.y;
    const int qtile = blockIdx.x;        // 256-query tile

    const float* __restrict__ qraw = (dir ? x2 : x1) + (size_t)b * CN * 3;
    const float* __restrict__ traw = (dir ? x1 : x2) + (size_t)b * CM * 3;
    float* __restrict__ o = out + (dir ? ((size_t)CB * CN + (size_t)b * CM)
                                       : ((size_t)b * CN)) + qtile * QPB;

    // [tile][64]: entries 0-31 = rows' k0-3 words, 32-63 = rows' k4-7. 64 KB.
    __shared__ u32x2 AI[NTT * 64];

    const int tid  = threadIdx.x;
    const int lane = tid & 63;
    const int wave = __builtin_amdgcn_readfirstlane(tid >> 6);
    const int col  = lane & 31;
    const int h    = lane >> 5;

    // ---- Stage all 4096 targets: thread packs targets {tid + 512j}.
    // Per j: writes are two contiguous 256B runs -> conflict-free; global
    // reads coalesced (consecutive threads, consecutive 12B).
    #pragma unroll
    for (int j = 0; j < 8; ++j) {
        const int r = 512 * j + tid;
        const float* p = traw + 3 * r;
        float X = p[0], Y = p[1], Zc = p[2];
        float xl = X  - hi_f(X);
        float yl = Y  - hi_f(Y);
        float zl = Zc - hi_f(Zc);
        float nt  = fmaf(X, X, fmaf(Y, Y, Zc * Zc));
        float ntl = nt - hi_f(nt);
        const int e = (r >> 5) * 64 + (r & 31);
        AI[e]      = (u32x2){pack2(X, Y),   pack2(Zc, xl)};   // k0..k3
        AI[e + 32] = (u32x2){pack2(yl, zl), pack2(nt, ntl)};  // k4..k7
    }

    // ---- Query: wave covers [qtile*256 + wave*32, +32); lane's col.
    // B m-terms RNE-rounded (halves the uncompensated q-side error), then
    // pack2 so the halfword convention matches A exactly.
    float nq;
    bf16x4 bq;
    {
        const float* qp = qraw + (size_t)3 * (qtile * QPB + wave * QPW + col);
        float qx = qp[0], qy = qp[1], qz = qp[2];
        nq = fmaf(qx, qx, fmaf(qy, qy, qz * qz));
        float mx = rne_bf(-2.f * qx);
        float my = rne_bf(-2.f * qy);
        float mz = rne_bf(-2.f * qz);
        u32x2 w;
        if (h == 0)
            w = (u32x2){pack2(mx, my), pack2(mz, mx)};        // k0..k3
        else
            w = (u32x2){pack2(my, mz), pack2(1.0f, 1.0f)};    // k4..k7
        bq = __builtin_bit_cast(bf16x4, w);
    }

    float best = 1e30f;
    __syncthreads();

    // ---- Sweep 128 tiles: 1 ds_read_b64 + 1 MFMA + 16-fminf tree. Unroll 4.
    #pragma unroll 1
    for (int t = 0; t < NTT; t += 4) {
        #pragma unroll
        for (int u = 0; u < 4; ++u) {
            bf16x4 af = __builtin_bit_cast(bf16x4, AI[(t + u) * 64 + lane]);
            f32x16 acc = __builtin_amdgcn_mfma_f32_32x32x8bf16_1k(
                af, bq, (f32x16)(0.f), 0, 0, 0);
            float t0 = fminf(fminf(acc[0],  acc[1]),  acc[2]);
            float t1 = fminf(fminf(acc[3],  acc[4]),  acc[5]);
            float t2 = fminf(fminf(acc[6],  acc[7]),  acc[8]);
            float t3 = fminf(fminf(acc[9],  acc[10]), acc[11]);
            float t4 = fminf(fminf(acc[12], acc[13]), acc[14]);
            float u0 = fminf(fminf(t0, t1), t2);
            float u1 = fminf(fminf(t3, t4), acc[15]);
            best = fminf(fminf(best, u0), u1);
        }
    }

    // ---- Combine the two half-row groups, add |q|^2, clamp, direct store.
    float v = fminf(best, __shfl_xor(best, 32));
    if (lane < 32)
        o[wave * QPW + col] = fmaxf(v + nq, 0.f);
}

extern "C" void kernel_launch(void* const* d_in, const int* in_sizes, int n_in,
                              void* d_out, int out_size, void* d_ws, size_t ws_size,
                              hipStream_t stream) {
    const float* x1 = (const float*)d_in[0];   // [B,N,3]
    const float* x2 = (const float*)d_in[1];   // [B,M,3]
    float* out = (float*)d_out;

    chamfer_mfma<<<dim3(16, CB, 2), 512, 0, stream>>>(x1, x2, out);
}